// Round 5
// baseline (860.695 us; speedup 1.0000x reference)
//
#include <hip/hip_runtime.h>
#include <hip/hip_bf16.h>
#include <stdint.h>

#define NV 100000   // nodes
#define NT 8        // edge types
#define NE 400000   // edges per type
#define ND 128      // feature dim
#define NTV (NT * NV)                 // 800000 (t,v) pairs
#define SC1B ((NTV + 1023) / 1024)    // 782 scan blocks
#define XCVT ((NV * ND / 8) / 256)    // 6250 blocks for x-convert

typedef float  f32x4  __attribute__((ext_vector_type(4)));
typedef short  bf16x8 __attribute__((ext_vector_type(8)));

static __device__ __forceinline__ unsigned short f2bf(float f) {
    unsigned u = __float_as_uint(f);
    u += 0x7fffu + ((u >> 16) & 1u);   // RNE
    return (unsigned short)(u >> 16);
}

// degree counts for src (cs) and dest (cd); 4 edges/thread via int4
__global__ __launch_bounds__(256) void k_count(const int* __restrict__ edges,
                                               unsigned* __restrict__ cs,
                                               unsigned* __restrict__ cd) {
    int i = blockIdx.x * 256 + threadIdx.x;          // NT*NE/4 threads
    if (i >= NT * NE / 4) return;
    int t = i / (NE / 4);
    int e = (i - t * (NE / 4)) * 4;
    const int* base = edges + (size_t)t * 2 * NE;
    int4 s4 = *(const int4*)&base[e];
    int4 d4 = *(const int4*)&base[NE + e];
    unsigned* cst = cs + t * NV;
    unsigned* cdt = cd + t * NV;
    atomicAdd(&cst[s4.x], 1u); atomicAdd(&cst[s4.y], 1u);
    atomicAdd(&cst[s4.z], 1u); atomicAdd(&cst[s4.w], 1u);
    atomicAdd(&cdt[d4.x], 1u); atomicAdd(&cdt[d4.y], 1u);
    atomicAdd(&cdt[d4.z], 1u); atomicAdd(&cdt[d4.w], 1u);
}

// ---- exclusive scan of cd (800000 u32) -> off ----
__global__ __launch_bounds__(256) void k_scan1(const unsigned* __restrict__ cnt,
                                               unsigned* __restrict__ off,
                                               unsigned* __restrict__ bsum) {
    __shared__ unsigned sm[256];
    int tid  = threadIdx.x;
    int base = blockIdx.x * 1024 + tid * 4;
    unsigned v0 = (base + 0 < NTV) ? cnt[base + 0] : 0u;
    unsigned v1 = (base + 1 < NTV) ? cnt[base + 1] : 0u;
    unsigned v2 = (base + 2 < NTV) ? cnt[base + 2] : 0u;
    unsigned v3 = (base + 3 < NTV) ? cnt[base + 3] : 0u;
    unsigned s4 = v0 + v1 + v2 + v3;
    sm[tid] = s4;
    __syncthreads();
    for (int d = 1; d < 256; d <<= 1) {
        unsigned tv = (tid >= d) ? sm[tid - d] : 0u;
        __syncthreads();
        sm[tid] += tv;
        __syncthreads();
    }
    unsigned excl = sm[tid] - s4;
    if (tid == 255) bsum[blockIdx.x] = sm[255];
    if (base + 0 < NTV) off[base + 0] = excl;
    if (base + 1 < NTV) off[base + 1] = excl + v0;
    if (base + 2 < NTV) off[base + 2] = excl + v0 + v1;
    if (base + 3 < NTV) off[base + 3] = excl + v0 + v1 + v2;
}

__global__ __launch_bounds__(1024) void k_scan2(unsigned* __restrict__ bsum) {
    __shared__ unsigned sm[1024];
    int tid = threadIdx.x;
    unsigned v = (tid < SC1B) ? bsum[tid] : 0u;
    sm[tid] = v;
    __syncthreads();
    for (int d = 1; d < 1024; d <<= 1) {
        unsigned tv = (tid >= d) ? sm[tid - d] : 0u;
        __syncthreads();
        sm[tid] += tv;
        __syncthreads();
    }
    if (tid < SC1B) bsum[tid] = sm[tid] - v;   // exclusive
}

// scan finalize + cursor copy + inv_ns (fused)
__global__ __launch_bounds__(256) void k_scan3(unsigned* __restrict__ off,
                                               const unsigned* __restrict__ bsum,
                                               unsigned* __restrict__ cursor,
                                               unsigned* __restrict__ cs) {
    int i = blockIdx.x * 256 + threadIdx.x;
    if (i < NTV) {
        unsigned v = off[i] + bsum[i >> 10];
        off[i]    = v;
        cursor[i] = v;
        unsigned a = cs[i];
        ((float*)cs)[i] = rsqrtf((float)(a > 1u ? a : 1u));
    }
    if (i == 0) off[NTV] = (unsigned)(NT * NE);
}

// fused converts: blocks [0,XCVT) do x f32->bf16; rest do W transpose+bf16
__global__ __launch_bounds__(256) void k_cvt(const float* __restrict__ x,
                                             unsigned short* __restrict__ xb,
                                             const float* __restrict__ W,
                                             unsigned short* __restrict__ Wt) {
    if (blockIdx.x < XCVT) {
        int i = blockIdx.x * 256 + threadIdx.x;
        const float4 a = *(const float4*)&x[(size_t)i * 8];
        const float4 b = *(const float4*)&x[(size_t)i * 8 + 4];
        union { unsigned short us[8]; uint4 v; } pk;
        pk.us[0] = f2bf(a.x); pk.us[1] = f2bf(a.y);
        pk.us[2] = f2bf(a.z); pk.us[3] = f2bf(a.w);
        pk.us[4] = f2bf(b.x); pk.us[5] = f2bf(b.y);
        pk.us[6] = f2bf(b.z); pk.us[7] = f2bf(b.w);
        *(uint4*)&xb[(size_t)i * 8] = pk.v;
    } else {
        int i = (blockIdx.x - XCVT) * 256 + threadIdx.x;   // NT*ND*ND = 131072
        int t = i >> 14;
        int r = i & 16383;
        int col = r >> 7;
        int k   = r & 127;
        Wt[i] = f2bf(W[((size_t)t * 128 + k) * 128 + col]);
    }
}

// CSR fill: bucket src by (t, dest); 4 edges/thread via int4
__global__ __launch_bounds__(256) void k_fill(const int* __restrict__ edges,
                                              unsigned* __restrict__ cursor,
                                              int* __restrict__ elist) {
    int i = blockIdx.x * 256 + threadIdx.x;          // NT*NE/4 threads
    if (i >= NT * NE / 4) return;
    int t = i / (NE / 4);
    int e = (i - t * (NE / 4)) * 4;
    const int* base = edges + (size_t)t * 2 * NE;
    int4 s4 = *(const int4*)&base[e];
    int4 d4 = *(const int4*)&base[NE + e];
    unsigned* curt = cursor + t * NV;
    unsigned p0 = atomicAdd(&curt[d4.x], 1u); elist[p0] = s4.x;
    unsigned p1 = atomicAdd(&curt[d4.y], 1u); elist[p1] = s4.y;
    unsigned p2 = atomicAdd(&curt[d4.z], 1u); elist[p2] = s4.z;
    unsigned p3 = atomicAdd(&curt[d4.w], 1u); elist[p3] = s4.w;
}

#define ACC8(dst, c, s)                                                      \
    do {                                                                     \
        (dst)[0] = fmaf(__uint_as_float((c).x << 16), (s), (dst)[0]);        \
        (dst)[1] = fmaf(__uint_as_float((c).x & 0xffff0000u), (s), (dst)[1]);\
        (dst)[2] = fmaf(__uint_as_float((c).y << 16), (s), (dst)[2]);        \
        (dst)[3] = fmaf(__uint_as_float((c).y & 0xffff0000u), (s), (dst)[3]);\
        (dst)[4] = fmaf(__uint_as_float((c).z << 16), (s), (dst)[4]);        \
        (dst)[5] = fmaf(__uint_as_float((c).z & 0xffff0000u), (s), (dst)[5]);\
        (dst)[6] = fmaf(__uint_as_float((c).w << 16), (s), (dst)[6]);        \
        (dst)[7] = fmaf(__uint_as_float((c).w & 0xffff0000u), (s), (dst)[7]);\
    } while (0)

// fused gather + (agg * inv_nd) @ W_t, accumulated over t in MFMA regs.
// EXACT round-3 body (known-good): register-resident A-fragments,
// inv_ns loaded at gather time, no unroll.
__global__ __launch_bounds__(256, 4) void k_fused(
    const unsigned short* __restrict__ xb, const unsigned short* __restrict__ Wt,
    const float* __restrict__ inv_ns, const unsigned* __restrict__ off,
    const int* __restrict__ elist, const float* __restrict__ bias,
    float* __restrict__ out)
{
    const int lane  = threadIdx.x & 63;
    const int wid   = threadIdx.x >> 6;
    const int row0  = blockIdx.x * 64 + wid * 16;
    const int arow  = lane & 15;
    const int g     = lane >> 4;
    const int myrow = row0 + arow;
    const bool rowok = (myrow < NV);
    const int rowi  = rowok ? myrow : 0;

    f32x4 acc[8];
#pragma unroll
    for (int cf = 0; cf < 8; ++cf) acc[cf] = (f32x4){0.f, 0.f, 0.f, 0.f};

    for (int t = 0; t < NT; ++t) {
        float ga[32];
#pragma unroll
        for (int j = 0; j < 32; ++j) ga[j] = 0.f;

        const int ti = t * NV + rowi;
        unsigned e0 = off[ti];
        unsigned e1 = rowok ? off[ti + 1] : e0;
        unsigned dd = e1 - e0;
        float snd = rsqrtf((float)(dd > 1u ? dd : 1u));
        const float* insb = inv_ns + (size_t)t * NV;

        for (unsigned e = e0; e < e1; ++e) {
            int   src = elist[e];
            float sns = insb[src];
            const uint4* xp = (const uint4*)(xb + (size_t)src * ND) + g;
            uint4 c0 = xp[0];
            uint4 c1 = xp[4];
            uint4 c2 = xp[8];
            uint4 c3 = xp[12];
            ACC8(ga + 0,  c0, sns);
            ACC8(ga + 8,  c1, sns);
            ACC8(ga + 16, c2, sns);
            ACC8(ga + 24, c3, sns);
        }

#pragma unroll
        for (int ks = 0; ks < 4; ++ks) {
            union { unsigned short u[8]; bf16x8 v; } af;
#pragma unroll
            for (int j = 0; j < 8; ++j) af.u[j] = f2bf(ga[ks * 8 + j] * snd);
#pragma unroll
            for (int cf = 0; cf < 8; ++cf) {
                const bf16x8 bf = *(const bf16x8*)&Wt[((size_t)(t * 128 + cf * 16 + arow)) * 128 + ks * 32 + g * 8];
                acc[cf] = __builtin_amdgcn_mfma_f32_16x16x32_bf16(af.v, bf, acc[cf], 0, 0, 0);
            }
        }
    }

    // C/D layout: col = lane&15, row = (lane>>4)*4 + i  [HW-verified]
#pragma unroll
    for (int i2 = 0; i2 < 4; ++i2) {
        int row = row0 + g * 4 + i2;
        if (row < NV) {
#pragma unroll
            for (int cf = 0; cf < 8; ++cf)
                out[(size_t)row * ND + cf * 16 + arow] = acc[cf][i2] + bias[cf * 16 + arow];
        }
    }
}

extern "C" void kernel_launch(void* const* d_in, const int* in_sizes, int n_in,
                              void* d_out, int out_size, void* d_ws, size_t ws_size,
                              hipStream_t stream) {
    const float* x     = (const float*)d_in[0];
    const int*   edges = (const int*)d_in[1];
    const float* W     = (const float*)d_in[2];
    const float* b     = (const float*)d_in[3];
    float*       out   = (float*)d_out;

    // ws layout: xb (25.6MB) | Wt (256KB) | cs | cd | off(+1) | bsum | cursor | elist
    unsigned short* xb     = (unsigned short*)d_ws;
    unsigned short* Wt     = xb + (size_t)NV * ND;
    unsigned*       cs     = (unsigned*)(Wt + (size_t)NT * ND * ND);
    unsigned*       cd     = cs + NTV;
    unsigned*       off    = cd + NTV;          // NTV+1
    unsigned*       bsum   = off + NTV + 1;     // 1024
    unsigned*       cursor = bsum + 1024;
    int*            elist  = (int*)(cursor + NTV);

    const size_t need = (size_t)NV * ND * 2 + (size_t)NT * ND * ND * 2 +
                        ((size_t)3 * NTV + (NTV + 1) + 1024) * 4 +
                        (size_t)NT * NE * 4;
    if (ws_size < need) return;

    hipMemsetAsync(cs, 0, (size_t)2 * NTV * sizeof(unsigned), stream);
    k_count<<<(NT * NE / 4 + 255) / 256, 256, 0, stream>>>(edges, cs, cd);
    k_scan1<<<SC1B, 256, 0, stream>>>(cd, off, bsum);
    k_scan2<<<1, 1024, 0, stream>>>(bsum);
    k_scan3<<<(NTV + 255) / 256, 256, 0, stream>>>(off, bsum, cursor, cs);
    k_cvt<<<XCVT + (NT * ND * ND) / 256, 256, 0, stream>>>(x, xb, W, Wt);
    k_fill<<<(NT * NE / 4 + 255) / 256, 256, 0, stream>>>(edges, cursor, elist);
    k_fused<<<(NV + 63) / 64, 256, 0, stream>>>(xb, Wt, (const float*)cs, off, elist, b, out);
}

// Round 6
// 859.675 us; speedup vs baseline: 1.0012x; 1.0012x over previous
//
#include <hip/hip_runtime.h>
#include <hip/hip_bf16.h>
#include <stdint.h>

#define NV 100000   // nodes
#define NT 8        // edge types
#define NE 400000   // edges per type
#define ND 128      // feature dim
#define NTV (NT * NV)                 // 800000 (t,v) pairs
#define SC1B ((NTV + 1023) / 1024)    // 782 scan blocks
#define XCVT ((NV * ND / 8) / 256)    // 6250 blocks for x-convert

typedef float  f32x4  __attribute__((ext_vector_type(4)));
typedef short  bf16x8 __attribute__((ext_vector_type(8)));

static __device__ __forceinline__ unsigned short f2bf(float f) {
    unsigned u = __float_as_uint(f);
    u += 0x7fffu + ((u >> 16) & 1u);   // RNE
    return (unsigned short)(u >> 16);
}

// degree counts for src (cs) and dest (cd); 4 edges/thread via int4
__global__ __launch_bounds__(256) void k_count(const int* __restrict__ edges,
                                               unsigned* __restrict__ cs,
                                               unsigned* __restrict__ cd) {
    int i = blockIdx.x * 256 + threadIdx.x;          // NT*NE/4 threads
    if (i >= NT * NE / 4) return;
    int t = i / (NE / 4);
    int e = (i - t * (NE / 4)) * 4;
    const int* base = edges + (size_t)t * 2 * NE;
    int4 s4 = *(const int4*)&base[e];
    int4 d4 = *(const int4*)&base[NE + e];
    unsigned* cst = cs + t * NV;
    unsigned* cdt = cd + t * NV;
    atomicAdd(&cst[s4.x], 1u); atomicAdd(&cst[s4.y], 1u);
    atomicAdd(&cst[s4.z], 1u); atomicAdd(&cst[s4.w], 1u);
    atomicAdd(&cdt[d4.x], 1u); atomicAdd(&cdt[d4.y], 1u);
    atomicAdd(&cdt[d4.z], 1u); atomicAdd(&cdt[d4.w], 1u);
}

// ---- exclusive scan of cd (800000 u32) -> off ----
__global__ __launch_bounds__(256) void k_scan1(const unsigned* __restrict__ cnt,
                                               unsigned* __restrict__ off,
                                               unsigned* __restrict__ bsum) {
    __shared__ unsigned sm[256];
    int tid  = threadIdx.x;
    int base = blockIdx.x * 1024 + tid * 4;
    unsigned v0 = (base + 0 < NTV) ? cnt[base + 0] : 0u;
    unsigned v1 = (base + 1 < NTV) ? cnt[base + 1] : 0u;
    unsigned v2 = (base + 2 < NTV) ? cnt[base + 2] : 0u;
    unsigned v3 = (base + 3 < NTV) ? cnt[base + 3] : 0u;
    unsigned s4 = v0 + v1 + v2 + v3;
    sm[tid] = s4;
    __syncthreads();
    for (int d = 1; d < 256; d <<= 1) {
        unsigned tv = (tid >= d) ? sm[tid - d] : 0u;
        __syncthreads();
        sm[tid] += tv;
        __syncthreads();
    }
    unsigned excl = sm[tid] - s4;
    if (tid == 255) bsum[blockIdx.x] = sm[255];
    if (base + 0 < NTV) off[base + 0] = excl;
    if (base + 1 < NTV) off[base + 1] = excl + v0;
    if (base + 2 < NTV) off[base + 2] = excl + v0 + v1;
    if (base + 3 < NTV) off[base + 3] = excl + v0 + v1 + v2;
}

__global__ __launch_bounds__(1024) void k_scan2(unsigned* __restrict__ bsum) {
    __shared__ unsigned sm[1024];
    int tid = threadIdx.x;
    unsigned v = (tid < SC1B) ? bsum[tid] : 0u;
    sm[tid] = v;
    __syncthreads();
    for (int d = 1; d < 1024; d <<= 1) {
        unsigned tv = (tid >= d) ? sm[tid - d] : 0u;
        __syncthreads();
        sm[tid] += tv;
        __syncthreads();
    }
    if (tid < SC1B) bsum[tid] = sm[tid] - v;   // exclusive
}

// scan finalize + cursor copy + inv_ns (fused)
__global__ __launch_bounds__(256) void k_scan3(unsigned* __restrict__ off,
                                               const unsigned* __restrict__ bsum,
                                               unsigned* __restrict__ cursor,
                                               unsigned* __restrict__ cs) {
    int i = blockIdx.x * 256 + threadIdx.x;
    if (i < NTV) {
        unsigned v = off[i] + bsum[i >> 10];
        off[i]    = v;
        cursor[i] = v;
        unsigned a = cs[i];
        ((float*)cs)[i] = rsqrtf((float)(a > 1u ? a : 1u));
    }
    if (i == 0) off[NTV] = (unsigned)(NT * NE);
}

// fused converts: blocks [0,XCVT) do x f32->bf16; rest do W transpose+bf16
__global__ __launch_bounds__(256) void k_cvt(const float* __restrict__ x,
                                             unsigned short* __restrict__ xb,
                                             const float* __restrict__ W,
                                             unsigned short* __restrict__ Wt) {
    if (blockIdx.x < XCVT) {
        int i = blockIdx.x * 256 + threadIdx.x;
        const float4 a = *(const float4*)&x[(size_t)i * 8];
        const float4 b = *(const float4*)&x[(size_t)i * 8 + 4];
        union { unsigned short us[8]; uint4 v; } pk;
        pk.us[0] = f2bf(a.x); pk.us[1] = f2bf(a.y);
        pk.us[2] = f2bf(a.z); pk.us[3] = f2bf(a.w);
        pk.us[4] = f2bf(b.x); pk.us[5] = f2bf(b.y);
        pk.us[6] = f2bf(b.z); pk.us[7] = f2bf(b.w);
        *(uint4*)&xb[(size_t)i * 8] = pk.v;
    } else {
        int i = (blockIdx.x - XCVT) * 256 + threadIdx.x;   // NT*ND*ND = 131072
        int t = i >> 14;
        int r = i & 16383;
        int col = r >> 7;
        int k   = r & 127;
        Wt[i] = f2bf(W[((size_t)t * 128 + k) * 128 + col]);
    }
}

// CSR fill: bucket src by (t, dest); 4 edges/thread via int4
__global__ __launch_bounds__(256) void k_fill(const int* __restrict__ edges,
                                              unsigned* __restrict__ cursor,
                                              int* __restrict__ elist) {
    int i = blockIdx.x * 256 + threadIdx.x;          // NT*NE/4 threads
    if (i >= NT * NE / 4) return;
    int t = i / (NE / 4);
    int e = (i - t * (NE / 4)) * 4;
    const int* base = edges + (size_t)t * 2 * NE;
    int4 s4 = *(const int4*)&base[e];
    int4 d4 = *(const int4*)&base[NE + e];
    unsigned* curt = cursor + t * NV;
    unsigned p0 = atomicAdd(&curt[d4.x], 1u); elist[p0] = s4.x;
    unsigned p1 = atomicAdd(&curt[d4.y], 1u); elist[p1] = s4.y;
    unsigned p2 = atomicAdd(&curt[d4.z], 1u); elist[p2] = s4.z;
    unsigned p3 = atomicAdd(&curt[d4.w], 1u); elist[p3] = s4.w;
}

#define ACC8(dst, c, s)                                                      \
    do {                                                                     \
        (dst)[0] = fmaf(__uint_as_float((c).x << 16), (s), (dst)[0]);        \
        (dst)[1] = fmaf(__uint_as_float((c).x & 0xffff0000u), (s), (dst)[1]);\
        (dst)[2] = fmaf(__uint_as_float((c).y << 16), (s), (dst)[2]);        \
        (dst)[3] = fmaf(__uint_as_float((c).y & 0xffff0000u), (s), (dst)[3]);\
        (dst)[4] = fmaf(__uint_as_float((c).z << 16), (s), (dst)[4]);        \
        (dst)[5] = fmaf(__uint_as_float((c).z & 0xffff0000u), (s), (dst)[5]);\
        (dst)[6] = fmaf(__uint_as_float((c).w << 16), (s), (dst)[6]);        \
        (dst)[7] = fmaf(__uint_as_float((c).w & 0xffff0000u), (s), (dst)[7]);\
    } while (0)

// fused gather + (agg * inv_nd) @ W_t, accumulated over t in MFMA regs.
// Round-3 numerics (identical edge order / ACC8 sequence) with a
// software pipeline: src index prefetched 2 ahead, row data + scale
// prefetched 1 ahead in named (statically-indexed) registers.
__global__ __launch_bounds__(256, 4) void k_fused(
    const unsigned short* __restrict__ xb, const unsigned short* __restrict__ Wt,
    const float* __restrict__ inv_ns, const unsigned* __restrict__ off,
    const int* __restrict__ elist, const float* __restrict__ bias,
    float* __restrict__ out)
{
    const int lane  = threadIdx.x & 63;
    const int wid   = threadIdx.x >> 6;
    const int row0  = blockIdx.x * 64 + wid * 16;
    const int arow  = lane & 15;
    const int g     = lane >> 4;
    const int myrow = row0 + arow;
    const bool rowok = (myrow < NV);
    const int rowi  = rowok ? myrow : 0;

    f32x4 acc[8];
#pragma unroll
    for (int cf = 0; cf < 8; ++cf) acc[cf] = (f32x4){0.f, 0.f, 0.f, 0.f};

    for (int t = 0; t < NT; ++t) {
        float ga[32];
#pragma unroll
        for (int j = 0; j < 32; ++j) ga[j] = 0.f;

        const int ti = t * NV + rowi;
        unsigned e0 = off[ti];
        unsigned e1 = rowok ? off[ti + 1] : e0;
        unsigned dd = e1 - e0;
        float snd = rsqrtf((float)(dd > 1u ? dd : 1u));
        const float* insb = inv_ns + (size_t)t * NV;

        unsigned e = e0;
        if (e < e1) {
            const unsigned e1m = e1 - 1;
            // prologue: current edge's row + scale, next edge's src
            int csrc = elist[e];
            float csns = insb[csrc];
            const uint4* xp = (const uint4*)(xb + (size_t)csrc * ND) + g;
            uint4 c0 = xp[0], c1 = xp[4], c2 = xp[8], c3 = xp[12];
            unsigned en = (e + 1 < e1) ? e + 1 : e1m;
            int nsrc = elist[en];
            do {
                // issue next row + scale (distance 1) and src (distance 2)
                const uint4* np = (const uint4*)(xb + (size_t)nsrc * ND) + g;
                uint4 n0 = np[0], n1 = np[4], n2 = np[8], n3 = np[12];
                float nsns = insb[nsrc];
                unsigned e2 = (e + 2 < e1) ? e + 2 : e1m;
                int asrc = elist[e2];
                // compute current (row regs loaded one iteration ago)
                ACC8(ga + 0,  c0, csns);
                ACC8(ga + 8,  c1, csns);
                ACC8(ga + 16, c2, csns);
                ACC8(ga + 24, c3, csns);
                // rotate pipeline (all static names, no dynamic indexing)
                c0 = n0; c1 = n1; c2 = n2; c3 = n3;
                csns = nsns; nsrc = asrc;
                ++e;
            } while (e < e1);
        }

#pragma unroll
        for (int ks = 0; ks < 4; ++ks) {
            union { unsigned short u[8]; bf16x8 v; } af;
#pragma unroll
            for (int j = 0; j < 8; ++j) af.u[j] = f2bf(ga[ks * 8 + j] * snd);
#pragma unroll
            for (int cf = 0; cf < 8; ++cf) {
                const bf16x8 bf = *(const bf16x8*)&Wt[((size_t)(t * 128 + cf * 16 + arow)) * 128 + ks * 32 + g * 8];
                acc[cf] = __builtin_amdgcn_mfma_f32_16x16x32_bf16(af.v, bf, acc[cf], 0, 0, 0);
            }
        }
    }

    // C/D layout: col = lane&15, row = (lane>>4)*4 + i  [HW-verified]
#pragma unroll
    for (int i2 = 0; i2 < 4; ++i2) {
        int row = row0 + g * 4 + i2;
        if (row < NV) {
#pragma unroll
            for (int cf = 0; cf < 8; ++cf)
                out[(size_t)row * ND + cf * 16 + arow] = acc[cf][i2] + bias[cf * 16 + arow];
        }
    }
}

extern "C" void kernel_launch(void* const* d_in, const int* in_sizes, int n_in,
                              void* d_out, int out_size, void* d_ws, size_t ws_size,
                              hipStream_t stream) {
    const float* x     = (const float*)d_in[0];
    const int*   edges = (const int*)d_in[1];
    const float* W     = (const float*)d_in[2];
    const float* b     = (const float*)d_in[3];
    float*       out   = (float*)d_out;

    // ws layout: xb (25.6MB) | Wt (256KB) | cs | cd | off(+1) | bsum | cursor | elist
    unsigned short* xb     = (unsigned short*)d_ws;
    unsigned short* Wt     = xb + (size_t)NV * ND;
    unsigned*       cs     = (unsigned*)(Wt + (size_t)NT * ND * ND);
    unsigned*       cd     = cs + NTV;
    unsigned*       off    = cd + NTV;          // NTV+1
    unsigned*       bsum   = off + NTV + 1;     // 1024
    unsigned*       cursor = bsum + 1024;
    int*            elist  = (int*)(cursor + NTV);

    const size_t need = (size_t)NV * ND * 2 + (size_t)NT * ND * ND * 2 +
                        ((size_t)3 * NTV + (NTV + 1) + 1024) * 4 +
                        (size_t)NT * NE * 4;
    if (ws_size < need) return;

    hipMemsetAsync(cs, 0, (size_t)2 * NTV * sizeof(unsigned), stream);
    k_count<<<(NT * NE / 4 + 255) / 256, 256, 0, stream>>>(edges, cs, cd);
    k_scan1<<<SC1B, 256, 0, stream>>>(cd, off, bsum);
    k_scan2<<<1, 1024, 0, stream>>>(bsum);
    k_scan3<<<(NTV + 255) / 256, 256, 0, stream>>>(off, bsum, cursor, cs);
    k_cvt<<<XCVT + (NT * ND * ND) / 256, 256, 0, stream>>>(x, xb, W, Wt);
    k_fill<<<(NT * NE / 4 + 255) / 256, 256, 0, stream>>>(edges, cursor, elist);
    k_fused<<<(NV + 63) / 64, 256, 0, stream>>>(xb, Wt, (const float*)cs, off, elist, b, out);
}